// Round 12
// baseline (467.886 us; speedup 1.0000x reference)
//
#include <hip/hip_runtime.h>

#define N_NODES 100000
#define N_EDGES 800000
#define F_IN    75
#define HID     100
#define SP      112            // padded fp16 row stride (halves) for intermediates
#define XSTR    80             // fp16 row stride for converted input
#define NROWS   100096         // rows padded to multiple of 128
#define BN_EPS  1e-5f
#define LSTR    136            // LDS row stride (halves)
#define NBKT    128            // dst-range buckets
#define NPB     782            // nodes per bucket
#define BIN_CAP 8192           // per-bucket global capacity
#define SBCAP   64             // per-bucket LDS staging capacity in k_bin

typedef _Float16 h8 __attribute__((ext_vector_type(8)));
typedef float    f4 __attribute__((ext_vector_type(4)));

// ------------- binning: edges -> 128 dst-range buckets (coalesced appends) -----------

__global__ __launch_bounds__(256) void k_bin(const int* __restrict__ ei,
                                             int* __restrict__ bcur,
                                             int2* __restrict__ bkt) {
    __shared__ int2 sb[NBKT * SBCAP];               // 64 KB
    __shared__ int scur[NBKT], sbase[NBKT], spre[NBKT];
    int tid = threadIdx.x;
    for (int i = tid; i < NBKT; i += 256) scur[i] = 0;
    __syncthreads();
    int base = blockIdx.x * 2048;
#pragma unroll
    for (int j = 0; j < 8; ++j) {
        int e = base + j * 256 + tid;
        if (e < N_EDGES) {
            int s = __builtin_nontemporal_load(&ei[e]);
            int d = __builtin_nontemporal_load(&ei[N_EDGES + e]);
            int b = d / NPB;
            int p = atomicAdd(&scur[b], 1);
            if (p < SBCAP) sb[b * SBCAP + p] = make_int2(s, d);
            else {
                int gp = atomicAdd(&bcur[b], 1);
                bkt[(size_t)b * BIN_CAP + gp] = make_int2(s, d);
            }
        }
    }
    __syncthreads();
    if (tid < NBKT) {
        int c = scur[tid]; if (c > SBCAP) c = SBCAP;
        scur[tid] = c;
        sbase[tid] = atomicAdd(&bcur[tid], c);
    }
    __syncthreads();
    if (tid < NBKT) {
        int lane = tid & 63;
        int x = scur[tid];
#pragma unroll
        for (int off = 1; off < 64; off <<= 1) {
            int y = __shfl_up(x, off);
            if (lane >= off) x += y;
        }
        spre[tid] = x;
    }
    __syncthreads();
    if (tid >= 64 && tid < NBKT) spre[tid] += spre[63];
    __syncthreads();
    int total = spre[NBKT - 1];
    for (int t = tid; t < total; t += 256) {
        int lo = 0, hi = NBKT - 1;
        while (lo < hi) { int mid = (lo + hi) >> 1; if (spre[mid] > t) hi = mid; else lo = mid + 1; }
        int bb = lo;
        int local = t - (spre[bb] - scur[bb]);
        bkt[(size_t)bb * BIN_CAP + sbase[bb] + local] = sb[bb * SBCAP + local];
    }
}

// ------------- per-bucket: LDS count + scan + rowp/dinv + csr scatter ---------------

__global__ __launch_bounds__(256) void k_local(const int* __restrict__ bcur,
                                               const int2* __restrict__ bkt,
                                               int* __restrict__ rowp,
                                               float* __restrict__ dinv,
                                               int* __restrict__ csr) {
    __shared__ int lcnt[1024];
    __shared__ int lofs[1024];
    __shared__ int sbc[NBKT];
    __shared__ int swt[4];
    __shared__ int gbase_s;
    int b = blockIdx.x, tid = threadIdx.x;
    for (int i = tid; i < 1024; i += 256) lcnt[i] = 0;
    if (tid < NBKT) sbc[tid] = bcur[tid];
    __syncthreads();
    if (tid == 0) { int s = 0; for (int j = 0; j < b; ++j) s += sbc[j]; gbase_s = s; }
    int cnt = sbc[b];
    const int2* bp = bkt + (size_t)b * BIN_CAP;
    int base_node = b * NPB;
    for (int i = tid; i < cnt; i += 256)
        atomicAdd(&lcnt[bp[i].y - base_node], 1);
    __syncthreads();
    int i0 = tid * 4;
    int c0 = lcnt[i0], c1 = lcnt[i0 + 1], c2 = lcnt[i0 + 2], c3 = lcnt[i0 + 3];
    int s = c0 + c1 + c2 + c3;
    int lane = tid & 63, wid = tid >> 6;
    int x = s;
#pragma unroll
    for (int off = 1; off < 64; off <<= 1) {
        int y = __shfl_up(x, off);
        if (lane >= off) x += y;
    }
    if (lane == 63) swt[wid] = x;
    __syncthreads();
    int woff = 0;
    for (int wv = 0; wv < wid; ++wv) woff += swt[wv];
    int excl = woff + x - s;
    lofs[i0] = excl;
    lofs[i0 + 1] = excl + c0;
    lofs[i0 + 2] = excl + c0 + c1;
    lofs[i0 + 3] = excl + c0 + c1 + c2;
    __syncthreads();
    int gbase = gbase_s;
    for (int i = tid; i < NPB; i += 256) {
        int node = base_node + i;
        if (node < N_NODES) {
            rowp[node] = gbase + lofs[i];
            dinv[node] = rsqrtf((float)(lcnt[i] + 1));
        }
    }
    if (b == NBKT - 1 && tid == 0) rowp[N_NODES] = N_EDGES;
    __syncthreads();
    for (int i = tid; i < cnt; i += 256) {
        int2 p = bp[i];
        int pos = atomicAdd(&lofs[p.y - base_node], 1);
        csr[gbase + pos] = p.x;
    }
}

// -------- x -> fp16 * dinv[row] (stride 80, zero pad cols 75..79, rows >= N) --------

__global__ __launch_bounds__(256) void k_cvt(const float* __restrict__ x,
                                             const float* __restrict__ dinv,
                                             _Float16* __restrict__ xh) {
    int id = blockIdx.x * 256 + threadIdx.x;        // NROWS*10 chunks
    int r = id / 10, c0 = (id - r * 10) * 8;
    h8 o;
#pragma unroll
    for (int j = 0; j < 8; ++j) o[j] = (_Float16)0.f;
    if (r < N_NODES) {
        float dv = dinv[r];
        const float* xr = x + (size_t)r * F_IN;
#pragma unroll
        for (int j = 0; j < 8; ++j) {
            int c = c0 + j;
            if (c < F_IN) o[j] = (_Float16)(__builtin_nontemporal_load(&xr[c]) * dv);
        }
    }
    *(h8*)&xh[(size_t)r * XSTR + c0] = o;
}

// ---------------- weight swizzle + param folding ----------------
// mats 0,1,2 (GCN): plain swizzle. mats 3,4 (head): BN folded; bfold[0|128]=b*s+t.
// aggp[layer 0,1,2][3][128]: GCN (b, s, t).

__global__ __launch_bounds__(128) void k_swz(
    const float* __restrict__ W1, const float* __restrict__ W2,
    const float* __restrict__ W3, const float* __restrict__ fW1,
    const float* __restrict__ fW2,
    const float* __restrict__ b1, const float* __restrict__ g1,
    const float* __restrict__ be1, const float* __restrict__ m1,
    const float* __restrict__ v1,
    const float* __restrict__ b2, const float* __restrict__ g2,
    const float* __restrict__ be2, const float* __restrict__ m2,
    const float* __restrict__ v2,
    const float* __restrict__ b3, const float* __restrict__ g3,
    const float* __restrict__ be3, const float* __restrict__ m3,
    const float* __restrict__ v3,
    const float* __restrict__ fb1, const float* __restrict__ fg1,
    const float* __restrict__ fbe1, const float* __restrict__ fm1,
    const float* __restrict__ fv1,
    const float* __restrict__ fb2, const float* __restrict__ fg2,
    const float* __restrict__ fbe2, const float* __restrict__ fm2,
    const float* __restrict__ fv2,
    h8* __restrict__ wsw, float* __restrict__ bfold, float* __restrict__ aggp) {
    int mat = blockIdx.x >> 3, tile = blockIdx.x & 7;
    int tid = threadIdx.x;

    if (mat == 5) {                       // agg params: tile 0,1,2 -> GCN layers 1,2,3
        if (tile > 2) return;
        const float *bb, *gg, *be, *mm, *vv;
        if (tile == 0) { bb = b1; gg = g1; be = be1; mm = m1; vv = v1; }
        else if (tile == 1) { bb = b2; gg = g2; be = be2; mm = m2; vv = v2; }
        else { bb = b3; gg = g3; be = be3; mm = m3; vv = v3; }
        int c = tid;
        float b = 0.f, s = 0.f, t = 0.f;
        if (c < HID) {
            b = bb[c];
            s = gg[c] * rsqrtf(vv[c] + BN_EPS);
            t = be[c] - mm[c] * s;
        }
        aggp[tile * 384 + c] = b;
        aggp[tile * 384 + 128 + c] = s;
        aggp[tile * 384 + 256 + c] = t;
        return;
    }

    const float* W; int K;
    const float *bb = nullptr, *gg = nullptr, *be = nullptr, *mm = nullptr, *vv = nullptr;
    bool fold = false;
    switch (mat) {
        case 0: W = W1; K = F_IN; break;
        case 1: W = W2; K = HID; break;
        case 2: W = W3; K = HID; break;
        case 3: W = fW1; K = HID; fold = true; bb = fb1; gg = fg1; be = fbe1; mm = fm1; vv = fv1; break;
        default: W = fW2; K = HID; fold = true; bb = fb2; gg = fg2; be = fbe2; mm = fm2; vv = fv2; break;
    }
    if (tid < 64) {
        int m16 = tid & 15, q = tid >> 4;
        int n = tile * 16 + m16;
        float sn = 1.f;
        if (fold && n < HID) sn = gg[n] * rsqrtf(vv[n] + BN_EPS);
        for (int kc = 0; kc < 4; ++kc) {
            h8 b;
#pragma unroll
            for (int j = 0; j < 8; ++j) {
                int k = kc * 32 + q * 8 + j;
                float v = (k < K && n < HID) ? W[k * HID + n] * sn : 0.f;
                b[j] = (_Float16)v;
            }
            wsw[((size_t)mat * 8 + tile) * 256 + kc * 64 + tid] = b;
        }
    }
    if (fold && tile == 0) {
        int c = tid;
        float v = 0.f;
        if (c < HID) {
            float s = gg[c] * rsqrtf(vv[c] + BN_EPS);
            float t = be[c] - mm[c] * s;
            v = bb[c] * s + t;
        }
        bfold[(mat - 3) * 128 + c] = v;
    }
}

// ---------------- agg phase (device): gather 8 rows per quarter-wave into LDS -------
// AMODE 0: row = sum * dinv[n]               (layer-1 aggregate of xh)
// AMODE 1: row = relu(sum*dinv + b)*s + t    (GCN layers 2,3: bias+relu+BN)
// Lanes sub in [ASTR/8, ZEND) write zero pad chunks.

template <int ASTR, int AMODE, int ZEND>
__device__ __forceinline__ void agg_phase(
    const _Float16* __restrict__ src, const int* __restrict__ rowp,
    const int* __restrict__ csr, const float* __restrict__ dinv,
    const float* __restrict__ prm, _Float16* __restrict__ As,
    int rowbase, int tid) {
    const int qw = tid >> 4, sub = tid & 15;
    constexpr int NCH = ASTR / 8;
    const int co = sub * 8;

    if (sub >= NCH) {
        if (sub < ZEND) {
            h8 z;
#pragma unroll
            for (int j = 0; j < 8; ++j) z[j] = (_Float16)0.f;
#pragma unroll
            for (int i = 0; i < 8; ++i)
                *(h8*)&As[(qw * 8 + i) * LSTR + co] = z;
        }
        return;
    }

    float bl[8], sl[8], tl[8];
    if (AMODE == 1) {
#pragma unroll
        for (int j = 0; j < 8; ++j) {
            bl[j] = prm[co + j]; sl[j] = prm[128 + co + j]; tl[j] = prm[256 + co + j];
        }
    }

    for (int i = 0; i < 8; ++i) {
        int n = rowbase + qw * 8 + i;
        float acc[8];
        if (n < N_NODES) {
            h8 v = *(const h8*)&src[(size_t)n * ASTR + co];
#pragma unroll
            for (int j = 0; j < 8; ++j) acc[j] = (float)v[j];
            int e = rowp[n], end = rowp[n + 1];
            for (; e + 7 < end; e += 8) {
                int s0 = csr[e],     s1 = csr[e + 1], s2 = csr[e + 2], s3 = csr[e + 3];
                int s4 = csr[e + 4], s5 = csr[e + 5], s6 = csr[e + 6], s7 = csr[e + 7];
                h8 v0 = *(const h8*)&src[(size_t)s0 * ASTR + co];
                h8 v1 = *(const h8*)&src[(size_t)s1 * ASTR + co];
                h8 v2 = *(const h8*)&src[(size_t)s2 * ASTR + co];
                h8 v3 = *(const h8*)&src[(size_t)s3 * ASTR + co];
                h8 v4 = *(const h8*)&src[(size_t)s4 * ASTR + co];
                h8 v5 = *(const h8*)&src[(size_t)s5 * ASTR + co];
                h8 v6 = *(const h8*)&src[(size_t)s6 * ASTR + co];
                h8 v7 = *(const h8*)&src[(size_t)s7 * ASTR + co];
#pragma unroll
                for (int j = 0; j < 8; ++j)
                    acc[j] += (((float)v0[j] + (float)v1[j]) + ((float)v2[j] + (float)v3[j]))
                            + (((float)v4[j] + (float)v5[j]) + ((float)v6[j] + (float)v7[j]));
            }
            for (; e + 3 < end; e += 4) {
                int s0 = csr[e], s1 = csr[e + 1], s2 = csr[e + 2], s3 = csr[e + 3];
                h8 v0 = *(const h8*)&src[(size_t)s0 * ASTR + co];
                h8 v1 = *(const h8*)&src[(size_t)s1 * ASTR + co];
                h8 v2 = *(const h8*)&src[(size_t)s2 * ASTR + co];
                h8 v3 = *(const h8*)&src[(size_t)s3 * ASTR + co];
#pragma unroll
                for (int j = 0; j < 8; ++j)
                    acc[j] += ((float)v0[j] + (float)v1[j]) + ((float)v2[j] + (float)v3[j]);
            }
            for (; e < end; ++e) {
                int s = csr[e];
                h8 v = *(const h8*)&src[(size_t)s * ASTR + co];
#pragma unroll
                for (int j = 0; j < 8; ++j) acc[j] += (float)v[j];
            }
            float dv = dinv[n];
#pragma unroll
            for (int j = 0; j < 8; ++j) acc[j] *= dv;
        } else {
#pragma unroll
            for (int j = 0; j < 8; ++j) acc[j] = 0.f;
        }
        h8 o;
        if (AMODE == 1) {
#pragma unroll
            for (int j = 0; j < 8; ++j)
                o[j] = (_Float16)(fmaxf(acc[j] + bl[j], 0.f) * sl[j] + tl[j]);
        } else {
#pragma unroll
            for (int j = 0; j < 8; ++j) o[j] = (_Float16)acc[j];
        }
        *(h8*)&As[(qw * 8 + i) * LSTR + co] = o;
    }
}

// ---------------- MFMA phase (device): acc = As @ Bf ----------------

template <int KC>
__device__ __forceinline__ void mfma_phase(const _Float16* __restrict__ As,
                                           const h8 Bf[2][KC], f4 acc[8][2],
                                           int w, int m16, int q) {
#pragma unroll
    for (int mt = 0; mt < 8; ++mt) {
        acc[mt][0] = (f4){0.f, 0.f, 0.f, 0.f};
        acc[mt][1] = (f4){0.f, 0.f, 0.f, 0.f};
    }
#pragma unroll
    for (int kc = 0; kc < KC; ++kc) {
#pragma unroll
        for (int mt = 0; mt < 8; ++mt) {
            h8 a = *(const h8*)&As[(mt * 16 + m16) * LSTR + kc * 32 + q * 8];
            acc[mt][0] = __builtin_amdgcn_mfma_f32_16x16x32_f16(a, Bf[0][kc], acc[mt][0], 0, 0, 0);
            if (w != 3)
                acc[mt][1] = __builtin_amdgcn_mfma_f32_16x16x32_f16(a, Bf[1][kc], acc[mt][1], 0, 0, 0);
        }
    }
}

// ---------------- fused agg + GEMM ----------------
// GMODE 0: out = acc * dinv[row];  GMODE 2: out = relu(acc+prm2)*prm2[128+]+prm2[256+]

template <int ASTR, int AMODE, int KC, int GMODE>
__global__ __launch_bounds__(256) void k_aggemm(
    const _Float16* __restrict__ src, const int* __restrict__ rowp,
    const int* __restrict__ csr, const float* __restrict__ dinv,
    const float* __restrict__ prm, const h8* __restrict__ Bsw,
    const float* __restrict__ prm2, _Float16* __restrict__ out) {
    __shared__ _Float16 As[128 * LSTR];
    const int tid = threadIdx.x;
    const int w = tid >> 6, l = tid & 63;
    const int m16 = l & 15, q = l >> 4;
    const int rowbase = blockIdx.x * 128;

    h8 Bf[2][KC];
#pragma unroll
    for (int ti = 0; ti < 2; ++ti)
#pragma unroll
        for (int kc = 0; kc < KC; ++kc)
            Bf[ti][kc] = Bsw[((w + ti * 4) * 4 + kc) * 64 + l];

    agg_phase<ASTR, AMODE, KC * 4>(src, rowp, csr, dinv, prm, As, rowbase, tid);
    __syncthreads();

    f4 acc[8][2];
    mfma_phase<KC>(As, Bf, acc, w, m16, q);
    __syncthreads();

    const int col0 = w * 16 + m16;
    const int col1 = col0 + 64;
    if (GMODE == 2) {
        float b0 = prm2[col0],       b1 = prm2[col1];
        float s0 = prm2[128 + col0], s1 = prm2[128 + col1];
        float t0 = prm2[256 + col0], t1 = prm2[256 + col1];
#pragma unroll
        for (int mt = 0; mt < 8; ++mt)
#pragma unroll
            for (int r = 0; r < 4; ++r) {
                int rl = mt * 16 + q * 4 + r;
                As[rl * LSTR + col0] = (_Float16)(fmaxf(acc[mt][0][r] + b0, 0.f) * s0 + t0);
                As[rl * LSTR + col1] = (_Float16)(fmaxf(acc[mt][1][r] + b1, 0.f) * s1 + t1);
            }
    } else {
#pragma unroll
        for (int mt = 0; mt < 8; ++mt)
#pragma unroll
            for (int r = 0; r < 4; ++r) {
                int rl = mt * 16 + q * 4 + r;
                int row = rowbase + rl;
                int dr = row < N_NODES ? row : N_NODES - 1;
                float dv = dinv[dr];
                As[rl * LSTR + col0] = (_Float16)(acc[mt][0][r] * dv);
                As[rl * LSTR + col1] = (_Float16)(acc[mt][1][r] * dv);
            }
    }
    __syncthreads();

    for (int i = tid; i < 128 * 14; i += 256) {
        int r = i / 14, c = i - r * 14;
        *(h8*)&out[(size_t)(rowbase + r) * SP + c * 8] = *(const h8*)&As[r * LSTR + c * 8];
    }
}

// ---------------- standalone GEMM (layer 2): out = (A @ W2) * dinv[row] ----------------

__global__ __launch_bounds__(256) void k_gemm(
    const _Float16* __restrict__ A, const h8* __restrict__ Bsw,
    const float* __restrict__ dinv, _Float16* __restrict__ out) {
    __shared__ _Float16 As[128 * LSTR];
    const int tid = threadIdx.x;
    const int w = tid >> 6, l = tid & 63;
    const int m16 = l & 15, q = l >> 4;
    const int rowbase = blockIdx.x * 128;

    h8 Bf[2][4];
#pragma unroll
    for (int ti = 0; ti < 2; ++ti)
#pragma unroll
        for (int kc = 0; kc < 4; ++kc)
            Bf[ti][kc] = Bsw[((w + ti * 4) * 4 + kc) * 64 + l];

    for (int i = tid; i < 128 * 14; i += 256) {
        int r = i / 14, c = i - r * 14;
        *(h8*)&As[r * LSTR + c * 8] = *(const h8*)&A[(size_t)(rowbase + r) * SP + c * 8];
    }
    {
        h8 z;
#pragma unroll
        for (int j = 0; j < 8; ++j) z[j] = (_Float16)0.f;
        for (int i = tid; i < 128 * 2; i += 256) {
            int r = i >> 1, c = 14 + (i & 1);
            *(h8*)&As[r * LSTR + c * 8] = z;
        }
    }
    __syncthreads();

    f4 acc[8][2];
    mfma_phase<4>(As, Bf, acc, w, m16, q);
    __syncthreads();

    const int col0 = w * 16 + m16;
    const int col1 = col0 + 64;
#pragma unroll
    for (int mt = 0; mt < 8; ++mt)
#pragma unroll
        for (int r = 0; r < 4; ++r) {
            int rl = mt * 16 + q * 4 + r;
            int row = rowbase + rl;
            int dr = row < N_NODES ? row : N_NODES - 1;
            float dv = dinv[dr];
            As[rl * LSTR + col0] = (_Float16)(acc[mt][0][r] * dv);
            As[rl * LSTR + col1] = (_Float16)(acc[mt][1][r] * dv);
        }
    __syncthreads();

    for (int i = tid; i < 128 * 14; i += 256) {
        int r = i / 14, c = i - r * 14;
        *(h8*)&out[(size_t)(rowbase + r) * SP + c * 8] = *(const h8*)&As[r * LSTR + c * 8];
    }
}

// ---------------- fused agg3 + dense head ----------------

__global__ __launch_bounds__(256) void k_aghead(
    const _Float16* __restrict__ src, const int* __restrict__ rowp,
    const int* __restrict__ csr, const float* __restrict__ dinv,
    const float* __restrict__ prm, const h8* __restrict__ Bsw3,
    const h8* __restrict__ Bsw4, const float* __restrict__ bfold1,
    const float* __restrict__ bfold2, const float* __restrict__ fW3,
    const float* __restrict__ fb3, float* __restrict__ out) {
    __shared__ _Float16 sh[128 * LSTR];
    const int tid = threadIdx.x;
    const int w = tid >> 6, l = tid & 63;
    const int m16 = l & 15, q = l >> 4;
    const int rowbase = blockIdx.x * 128;
    const int col0 = w * 16 + m16, col1 = col0 + 64;

    // agg3: h3 = BN3(relu(agg(z3)+b3)) into LDS
    agg_phase<SP, 1, 16>(src, rowp, csr, dinv, prm, sh, rowbase, tid);
    __syncthreads();

    h8 Bf[2][4];
    f4 acc[8][2];

    // GEMM fW1' (BN folded)
#pragma unroll
    for (int ti = 0; ti < 2; ++ti)
#pragma unroll
        for (int kc = 0; kc < 4; ++kc)
            Bf[ti][kc] = Bsw3[((w + ti * 4) * 4 + kc) * 64 + l];
    mfma_phase<4>(sh, Bf, acc, w, m16, q);
    __syncthreads();
    {
        float bf0 = bfold1[col0], bf1 = bfold1[col1];
#pragma unroll
        for (int mt = 0; mt < 8; ++mt)
#pragma unroll
            for (int r = 0; r < 4; ++r) {
                int rl = mt * 16 + q * 4 + r;
                sh[rl * LSTR + col0] = (_Float16)fmaxf(acc[mt][0][r] + bf0, 0.f);
                sh[rl * LSTR + col1] = (_Float16)fmaxf(acc[mt][1][r] + bf1, 0.f);
            }
    }
    __syncthreads();

    // GEMM fW2' (BN folded)
#pragma unroll
    for (int ti = 0; ti < 2; ++ti)
#pragma unroll
        for (int kc = 0; kc < 4; ++kc)
            Bf[ti][kc] = Bsw4[((w + ti * 4) * 4 + kc) * 64 + l];
    mfma_phase<4>(sh, Bf, acc, w, m16, q);
    __syncthreads();
    {
        float bf0 = bfold2[col0], bf1 = bfold2[col1];
#pragma unroll
        for (int mt = 0; mt < 8; ++mt)
#pragma unroll
            for (int r = 0; r < 4; ++r) {
                int rl = mt * 16 + q * 4 + r;
                sh[rl * LSTR + col0] = (_Float16)fmaxf(acc[mt][0][r] + bf0, 0.f);
                sh[rl * LSTR + col1] = (_Float16)fmaxf(acc[mt][1][r] + bf1, 0.f);
            }
    }
    __syncthreads();

    // 100 -> 3: quarter-wave per row (conflict-free reads) + 16-lane shfl reduce
    {
        const int qw = tid >> 4, sub = tid & 15;
        float w0 = fb3 ? 0.f : 0.f;  (void)w0;
#pragma unroll
        for (int pass = 0; pass < 8; ++pass) {
            int r = pass * 16 + qw;
            float p0 = 0.f, p1 = 0.f, p2 = 0.f;
            if (sub < 13) {
                h8 v = *(const h8*)&sh[r * LSTR + sub * 8];
#pragma unroll
                for (int jj = 0; jj < 8; ++jj) {
                    int c = sub * 8 + jj;
                    if (c < HID) {
                        float a = (float)v[jj];
                        p0 = fmaf(a, fW3[c * 3 + 0], p0);
                        p1 = fmaf(a, fW3[c * 3 + 1], p1);
                        p2 = fmaf(a, fW3[c * 3 + 2], p2);
                    }
                }
            }
#pragma unroll
            for (int mask = 1; mask < 16; mask <<= 1) {
                p0 += __shfl_xor(p0, mask);
                p1 += __shfl_xor(p1, mask);
                p2 += __shfl_xor(p2, mask);
            }
            if (sub == 0) {
                int grow = rowbase + r;
                if (grow < N_NODES) {
                    out[grow * 3 + 0] = fmaxf(p0 + fb3[0], 0.f);
                    out[grow * 3 + 1] = fmaxf(p1 + fb3[1], 0.f);
                    out[grow * 3 + 2] = fmaxf(p2 + fb3[2], 0.f);
                }
            }
        }
    }
}

// ---------------- launcher ----------------

extern "C" void kernel_launch(void* const* d_in, const int* in_sizes, int n_in,
                              void* d_out, int out_size, void* d_ws, size_t ws_size,
                              hipStream_t stream) {
    const float* x  = (const float*)d_in[0];
    const int*   ei = (const int*)d_in[1];
    const float* W1 = (const float*)d_in[2];  const float* b1 = (const float*)d_in[3];
    const float* g1 = (const float*)d_in[4];  const float* be1 = (const float*)d_in[5];
    const float* m1 = (const float*)d_in[6];  const float* v1 = (const float*)d_in[7];
    const float* W2 = (const float*)d_in[8];  const float* b2 = (const float*)d_in[9];
    const float* g2 = (const float*)d_in[10]; const float* be2 = (const float*)d_in[11];
    const float* m2 = (const float*)d_in[12]; const float* v2 = (const float*)d_in[13];
    const float* W3 = (const float*)d_in[14]; const float* b3 = (const float*)d_in[15];
    const float* g3 = (const float*)d_in[16]; const float* be3 = (const float*)d_in[17];
    const float* m3 = (const float*)d_in[18]; const float* v3 = (const float*)d_in[19];
    const float* fW1 = (const float*)d_in[20]; const float* fb1 = (const float*)d_in[21];
    const float* fg1 = (const float*)d_in[22]; const float* fbe1 = (const float*)d_in[23];
    const float* fm1 = (const float*)d_in[24]; const float* fv1 = (const float*)d_in[25];
    const float* fW2 = (const float*)d_in[26]; const float* fb2 = (const float*)d_in[27];
    const float* fg2 = (const float*)d_in[28]; const float* fbe2 = (const float*)d_in[29];
    const float* fm2 = (const float*)d_in[30]; const float* fv2 = (const float*)d_in[31];
    const float* fW3 = (const float*)d_in[32]; const float* fb3 = (const float*)d_in[33];
    float* out = (float*)d_out;

    char* w = (char*)d_ws;
    const size_t BUFS = (size_t)NROWS * SP * 2;         // 22,421,504 B
    _Float16* bufA = (_Float16*)(w);
    _Float16* bufB = (_Float16*)(w + BUFS);
    _Float16* xh   = (_Float16*)(w + 2 * BUFS);         // 16,015,360
    h8*    wsw   = (h8*)   (w + 60858368);              // 163,840
    float* bfold = (float*)(w + 61022208);              // 1,024
    float* aggp  = (float*)(w + 61023744);              // 4,608
    int*   bcur  = (int*)  (w + 61028352);              // 512
    int*   rowp  = (int*)  (w + 61028864);              // 400,128
    float* dinv  = (float*)(w + 61428992);              // 400,000
    int*   csr   = (int*)  (w + 61828992);              // 3,200,000
    int2*  bkt   = (int2*) (w + 65028992);              // 8,388,608 (end ~73.4 MB)

    (void)hipMemsetAsync(bcur, 0, NBKT * sizeof(int), stream);
    k_bin<<<(N_EDGES + 2047) / 2048, 256, 0, stream>>>(ei, bcur, bkt);
    k_local<<<NBKT, 256, 0, stream>>>(bcur, bkt, rowp, dinv, csr);
    k_cvt<<<NROWS * 10 / 256, 256, 0, stream>>>(x, dinv, xh);
    k_swz<<<48, 128, 0, stream>>>(W1, W2, W3, fW1, fW2,
                                  b1, g1, be1, m1, v1,
                                  b2, g2, be2, m2, v2,
                                  b3, g3, be3, m3, v3,
                                  fb1, fg1, fbe1, fm1, fv1,
                                  fb2, fg2, fbe2, fm2, fv2, wsw, bfold, aggp);

    const int ggrid = NROWS / 128;                      // 782

    // layer 1: [agg(xh) -> @W1, MODE2 epilogue] -> h1 (bufA)
    k_aggemm<XSTR, 0, 3, 2><<<ggrid, 256, 0, stream>>>(
        xh, rowp, csr, dinv, nullptr, wsw + 0 * 2048, aggp + 0 * 384, bufA);
    // layer 2 GEMM: z2 = (h1 @ W2) * dinv -> bufB
    k_gemm<<<ggrid, 256, 0, stream>>>(bufA, wsw + 1 * 2048, dinv, bufB);
    // layer 2 agg + layer 3 GEMM: [agg(z2)+BN2 -> @W3 * dinv] -> z3 (bufA)
    k_aggemm<SP, 1, 4, 0><<<ggrid, 256, 0, stream>>>(
        bufB, rowp, csr, dinv, aggp + 1 * 384, wsw + 2 * 2048, nullptr, bufA);
    // layer 3 agg + dense head
    k_aghead<<<ggrid, 256, 0, stream>>>(
        bufA, rowp, csr, dinv, aggp + 2 * 384, wsw + 3 * 2048, wsw + 4 * 2048,
        bfold, bfold + 128, fW3, fb3, out);
}

// Round 13
// 393.335 us; speedup vs baseline: 1.1895x; 1.1895x over previous
//
#include <hip/hip_runtime.h>

#define N_NODES 100000
#define N_EDGES 800000
#define F_IN    75
#define HID     100
#define SP      112            // padded fp16 row stride (halves) for intermediates
#define XSTR    80             // fp16 row stride for converted input
#define NROWS   100096         // rows padded to multiple of 128
#define BN_EPS  1e-5f
#define LSTR    136            // LDS row stride (halves)
#define NBKT    128            // dst-range buckets
#define NPB     782            // nodes per bucket
#define BIN_CAP 8192           // per-bucket global capacity
#define SBCAP   64             // per-bucket LDS staging capacity in k_bin

typedef _Float16 h8 __attribute__((ext_vector_type(8)));
typedef float    f4 __attribute__((ext_vector_type(4)));

// ------------- binning: edges -> 128 dst-range buckets (coalesced appends) -----------

__global__ __launch_bounds__(256) void k_bin(const int* __restrict__ ei,
                                             int* __restrict__ bcur,
                                             int2* __restrict__ bkt) {
    __shared__ int2 sb[NBKT * SBCAP];               // 64 KB
    __shared__ int scur[NBKT], sbase[NBKT], spre[NBKT];
    int tid = threadIdx.x;
    for (int i = tid; i < NBKT; i += 256) scur[i] = 0;
    __syncthreads();
    int base = blockIdx.x * 2048;
#pragma unroll
    for (int j = 0; j < 8; ++j) {
        int e = base + j * 256 + tid;
        if (e < N_EDGES) {
            int s = __builtin_nontemporal_load(&ei[e]);
            int d = __builtin_nontemporal_load(&ei[N_EDGES + e]);
            int b = d / NPB;
            int p = atomicAdd(&scur[b], 1);
            if (p < SBCAP) sb[b * SBCAP + p] = make_int2(s, d);
            else {
                int gp = atomicAdd(&bcur[b], 1);
                bkt[(size_t)b * BIN_CAP + gp] = make_int2(s, d);
            }
        }
    }
    __syncthreads();
    if (tid < NBKT) {
        int c = scur[tid]; if (c > SBCAP) c = SBCAP;
        scur[tid] = c;
        sbase[tid] = atomicAdd(&bcur[tid], c);
    }
    __syncthreads();
    if (tid < NBKT) {
        int lane = tid & 63;
        int x = scur[tid];
#pragma unroll
        for (int off = 1; off < 64; off <<= 1) {
            int y = __shfl_up(x, off);
            if (lane >= off) x += y;
        }
        spre[tid] = x;
    }
    __syncthreads();
    if (tid >= 64 && tid < NBKT) spre[tid] += spre[63];
    __syncthreads();
    int total = spre[NBKT - 1];
    for (int t = tid; t < total; t += 256) {
        int lo = 0, hi = NBKT - 1;
        while (lo < hi) { int mid = (lo + hi) >> 1; if (spre[mid] > t) hi = mid; else lo = mid + 1; }
        int bb = lo;
        int local = t - (spre[bb] - scur[bb]);
        bkt[(size_t)bb * BIN_CAP + sbase[bb] + local] = sb[bb * SBCAP + local];
    }
}

// ------------- per-bucket: LDS count + scan + rowp/dinv + csr scatter ---------------

__global__ __launch_bounds__(256) void k_local(const int* __restrict__ bcur,
                                               const int2* __restrict__ bkt,
                                               int* __restrict__ rowp,
                                               float* __restrict__ dinv,
                                               int* __restrict__ csr) {
    __shared__ int lcnt[1024];
    __shared__ int lofs[1024];
    __shared__ int sbc[NBKT];
    __shared__ int swt[4];
    __shared__ int gbase_s;
    int b = blockIdx.x, tid = threadIdx.x;
    for (int i = tid; i < 1024; i += 256) lcnt[i] = 0;
    if (tid < NBKT) sbc[tid] = bcur[tid];
    __syncthreads();
    if (tid == 0) { int s = 0; for (int j = 0; j < b; ++j) s += sbc[j]; gbase_s = s; }
    int cnt = sbc[b];
    const int2* bp = bkt + (size_t)b * BIN_CAP;
    int base_node = b * NPB;
    for (int i = tid; i < cnt; i += 256)
        atomicAdd(&lcnt[bp[i].y - base_node], 1);
    __syncthreads();
    int i0 = tid * 4;
    int c0 = lcnt[i0], c1 = lcnt[i0 + 1], c2 = lcnt[i0 + 2], c3 = lcnt[i0 + 3];
    int s = c0 + c1 + c2 + c3;
    int lane = tid & 63, wid = tid >> 6;
    int x = s;
#pragma unroll
    for (int off = 1; off < 64; off <<= 1) {
        int y = __shfl_up(x, off);
        if (lane >= off) x += y;
    }
    if (lane == 63) swt[wid] = x;
    __syncthreads();
    int woff = 0;
    for (int wv = 0; wv < wid; ++wv) woff += swt[wv];
    int excl = woff + x - s;
    lofs[i0] = excl;
    lofs[i0 + 1] = excl + c0;
    lofs[i0 + 2] = excl + c0 + c1;
    lofs[i0 + 3] = excl + c0 + c1 + c2;
    __syncthreads();
    int gbase = gbase_s;
    for (int i = tid; i < NPB; i += 256) {
        int node = base_node + i;
        if (node < N_NODES) {
            rowp[node] = gbase + lofs[i];
            dinv[node] = rsqrtf((float)(lcnt[i] + 1));
        }
    }
    if (b == NBKT - 1 && tid == 0) rowp[N_NODES] = N_EDGES;
    __syncthreads();
    for (int i = tid; i < cnt; i += 256) {
        int2 p = bp[i];
        int pos = atomicAdd(&lofs[p.y - base_node], 1);
        csr[gbase + pos] = p.x;
    }
}

// -------- x -> fp16 * dinv[row] (stride 80, zero pad cols 75..79, rows >= N) --------

__global__ __launch_bounds__(256) void k_cvt(const float* __restrict__ x,
                                             const float* __restrict__ dinv,
                                             _Float16* __restrict__ xh) {
    int id = blockIdx.x * 256 + threadIdx.x;        // NROWS*10 chunks
    int r = id / 10, c0 = (id - r * 10) * 8;
    h8 o;
#pragma unroll
    for (int j = 0; j < 8; ++j) o[j] = (_Float16)0.f;
    if (r < N_NODES) {
        float dv = dinv[r];
        const float* xr = x + (size_t)r * F_IN;
#pragma unroll
        for (int j = 0; j < 8; ++j) {
            int c = c0 + j;
            if (c < F_IN) o[j] = (_Float16)(__builtin_nontemporal_load(&xr[c]) * dv);
        }
    }
    *(h8*)&xh[(size_t)r * XSTR + c0] = o;
}

// ---------------- weight swizzle + param folding ----------------

__global__ __launch_bounds__(128) void k_swz(
    const float* __restrict__ W1, const float* __restrict__ W2,
    const float* __restrict__ W3, const float* __restrict__ fW1,
    const float* __restrict__ fW2,
    const float* __restrict__ b1, const float* __restrict__ g1,
    const float* __restrict__ be1, const float* __restrict__ m1,
    const float* __restrict__ v1,
    const float* __restrict__ b2, const float* __restrict__ g2,
    const float* __restrict__ be2, const float* __restrict__ m2,
    const float* __restrict__ v2,
    const float* __restrict__ b3, const float* __restrict__ g3,
    const float* __restrict__ be3, const float* __restrict__ m3,
    const float* __restrict__ v3,
    const float* __restrict__ fb1, const float* __restrict__ fg1,
    const float* __restrict__ fbe1, const float* __restrict__ fm1,
    const float* __restrict__ fv1,
    const float* __restrict__ fb2, const float* __restrict__ fg2,
    const float* __restrict__ fbe2, const float* __restrict__ fm2,
    const float* __restrict__ fv2,
    h8* __restrict__ wsw, float* __restrict__ bfold, float* __restrict__ aggp) {
    int mat = blockIdx.x >> 3, tile = blockIdx.x & 7;
    int tid = threadIdx.x;

    if (mat == 5) {                       // agg params: tile 0,1,2 -> GCN layers 1,2,3
        if (tile > 2) return;
        const float *bb, *gg, *be, *mm, *vv;
        if (tile == 0) { bb = b1; gg = g1; be = be1; mm = m1; vv = v1; }
        else if (tile == 1) { bb = b2; gg = g2; be = be2; mm = m2; vv = v2; }
        else { bb = b3; gg = g3; be = be3; mm = m3; vv = v3; }
        int c = tid;
        float b = 0.f, s = 0.f, t = 0.f;
        if (c < HID) {
            b = bb[c];
            s = gg[c] * rsqrtf(vv[c] + BN_EPS);
            t = be[c] - mm[c] * s;
        }
        aggp[tile * 384 + c] = b;
        aggp[tile * 384 + 128 + c] = s;
        aggp[tile * 384 + 256 + c] = t;
        return;
    }

    const float* W; int K;
    const float *bb = nullptr, *gg = nullptr, *be = nullptr, *mm = nullptr, *vv = nullptr;
    bool fold = false;
    switch (mat) {
        case 0: W = W1; K = F_IN; break;
        case 1: W = W2; K = HID; break;
        case 2: W = W3; K = HID; break;
        case 3: W = fW1; K = HID; fold = true; bb = fb1; gg = fg1; be = fbe1; mm = fm1; vv = fv1; break;
        default: W = fW2; K = HID; fold = true; bb = fb2; gg = fg2; be = fbe2; mm = fm2; vv = fv2; break;
    }
    if (tid < 64) {
        int m16 = tid & 15, q = tid >> 4;
        int n = tile * 16 + m16;
        float sn = 1.f;
        if (fold && n < HID) sn = gg[n] * rsqrtf(vv[n] + BN_EPS);
        for (int kc = 0; kc < 4; ++kc) {
            h8 b;
#pragma unroll
            for (int j = 0; j < 8; ++j) {
                int k = kc * 32 + q * 8 + j;
                float v = (k < K && n < HID) ? W[k * HID + n] * sn : 0.f;
                b[j] = (_Float16)v;
            }
            wsw[((size_t)mat * 8 + tile) * 256 + kc * 64 + tid] = b;
        }
    }
    if (fold && tile == 0) {
        int c = tid;
        float v = 0.f;
        if (c < HID) {
            float s = gg[c] * rsqrtf(vv[c] + BN_EPS);
            float t = be[c] - mm[c] * s;
            v = bb[c] * s + t;
        }
        bfold[(mat - 3) * 128 + c] = v;
    }
}

// ---------------- MFMA GEMM (128-row blocks) ----------------
// MODE 0: out = acc * dinv[row]
// MODE 2: out = relu(acc + prm[col]) * prm[128+col] + prm[256+col]   (GCN layer 1)

template <int KC, int ASTR, int MODE, int OSTR>
__global__ __launch_bounds__(256) void k_gemm(
    const _Float16* __restrict__ A, const h8* __restrict__ Bsw,
    const float* __restrict__ dinv, const float* __restrict__ prm,
    _Float16* __restrict__ out) {
    __shared__ _Float16 As[128 * LSTR];
    const int tid = threadIdx.x;
    const int w = tid >> 6, l = tid & 63;
    const int m16 = l & 15, q = l >> 4;
    const int rowbase = blockIdx.x * 128;

    h8 Bf[2][KC];
#pragma unroll
    for (int ti = 0; ti < 2; ++ti)
#pragma unroll
        for (int kc = 0; kc < KC; ++kc)
            Bf[ti][kc] = Bsw[((w + ti * 4) * 4 + kc) * 64 + l];

    constexpr int NCH = ASTR / 8;
    for (int i = tid; i < 128 * NCH; i += 256) {
        int r = i / NCH, c = i - r * NCH;
        *(h8*)&As[r * LSTR + c * 8] = *(const h8*)&A[(size_t)(rowbase + r) * ASTR + c * 8];
    }
    {
        constexpr int ZCH = (KC * 32 - ASTR) / 8;      // 2 in both configs
        h8 z;
#pragma unroll
        for (int j = 0; j < 8; ++j) z[j] = (_Float16)0.f;
        for (int i = tid; i < 128 * ZCH; i += 256) {
            int r = i / ZCH, c = NCH + (i - r * ZCH);
            *(h8*)&As[r * LSTR + c * 8] = z;
        }
    }
    __syncthreads();

    f4 acc[8][2];
#pragma unroll
    for (int mt = 0; mt < 8; ++mt) {
        acc[mt][0] = (f4){0.f, 0.f, 0.f, 0.f};
        acc[mt][1] = (f4){0.f, 0.f, 0.f, 0.f};
    }
#pragma unroll
    for (int kc = 0; kc < KC; ++kc) {
#pragma unroll
        for (int mt = 0; mt < 8; ++mt) {
            h8 a = *(const h8*)&As[(mt * 16 + m16) * LSTR + kc * 32 + q * 8];
            acc[mt][0] = __builtin_amdgcn_mfma_f32_16x16x32_f16(a, Bf[0][kc], acc[mt][0], 0, 0, 0);
            if (w != 3)
                acc[mt][1] = __builtin_amdgcn_mfma_f32_16x16x32_f16(a, Bf[1][kc], acc[mt][1], 0, 0, 0);
        }
    }
    __syncthreads();                                   // all MFMA LDS reads done

    const int col0 = w * 16 + m16;
    const int col1 = col0 + 64;
    if (MODE == 2) {
        float b0 = prm[col0],       b1 = prm[col1];
        float s0 = prm[128 + col0], s1 = prm[128 + col1];
        float t0 = prm[256 + col0], t1 = prm[256 + col1];
#pragma unroll
        for (int mt = 0; mt < 8; ++mt)
#pragma unroll
            for (int r = 0; r < 4; ++r) {
                int rl = mt * 16 + q * 4 + r;
                As[rl * LSTR + col0] = (_Float16)(fmaxf(acc[mt][0][r] + b0, 0.f) * s0 + t0);
                As[rl * LSTR + col1] = (_Float16)(fmaxf(acc[mt][1][r] + b1, 0.f) * s1 + t1);
            }
    } else {
#pragma unroll
        for (int mt = 0; mt < 8; ++mt)
#pragma unroll
            for (int r = 0; r < 4; ++r) {
                int rl = mt * 16 + q * 4 + r;
                int row = rowbase + rl;
                int dr = row < N_NODES ? row : N_NODES - 1;
                float dv = dinv[dr];
                As[rl * LSTR + col0] = (_Float16)(acc[mt][0][r] * dv);
                As[rl * LSTR + col1] = (_Float16)(acc[mt][1][r] * dv);
            }
    }
    __syncthreads();

    constexpr int OCH = OSTR / 8;                      // 14
    for (int i = tid; i < 128 * OCH; i += 256) {
        int r = i / OCH, c = i - r * OCH;
        *(h8*)&out[(size_t)(rowbase + r) * OSTR + c * 8] = *(const h8*)&As[r * LSTR + c * 8];
    }
}

// ------------- layer-1 aggregate on x (80 cols): ax = agg(xh)*dinv[n] ---------------

__global__ __launch_bounds__(256) void k_aggx(
    const _Float16* __restrict__ xh, const int* __restrict__ rowp,
    const int* __restrict__ csr, const float* __restrict__ dinv,
    _Float16* __restrict__ ax) {
    int l = threadIdx.x;
    int q = l >> 4, sub = l & 15;
    if (sub >= 10) return;                              // 80 cols
    int n = blockIdx.x * 16 + threadIdx.y * 4 + q;
    int co = sub * 8;
    int beg = rowp[n], end = rowp[n + 1];

    float acc[8];
    {
        h8 v = *(const h8*)&xh[(size_t)n * XSTR + co];  // self (already * dinv[n])
#pragma unroll
        for (int j = 0; j < 8; ++j) acc[j] = (float)v[j];
    }
    int e = beg;
    for (; e + 7 < end; e += 8) {
        int s0 = csr[e],     s1 = csr[e + 1], s2 = csr[e + 2], s3 = csr[e + 3];
        int s4 = csr[e + 4], s5 = csr[e + 5], s6 = csr[e + 6], s7 = csr[e + 7];
        h8 v0 = *(const h8*)&xh[(size_t)s0 * XSTR + co];
        h8 v1 = *(const h8*)&xh[(size_t)s1 * XSTR + co];
        h8 v2 = *(const h8*)&xh[(size_t)s2 * XSTR + co];
        h8 v3 = *(const h8*)&xh[(size_t)s3 * XSTR + co];
        h8 v4 = *(const h8*)&xh[(size_t)s4 * XSTR + co];
        h8 v5 = *(const h8*)&xh[(size_t)s5 * XSTR + co];
        h8 v6 = *(const h8*)&xh[(size_t)s6 * XSTR + co];
        h8 v7 = *(const h8*)&xh[(size_t)s7 * XSTR + co];
#pragma unroll
        for (int j = 0; j < 8; ++j)
            acc[j] += (((float)v0[j] + (float)v1[j]) + ((float)v2[j] + (float)v3[j]))
                    + (((float)v4[j] + (float)v5[j]) + ((float)v6[j] + (float)v7[j]));
    }
    for (; e + 3 < end; e += 4) {
        int s0 = csr[e], s1 = csr[e + 1], s2 = csr[e + 2], s3 = csr[e + 3];
        h8 v0 = *(const h8*)&xh[(size_t)s0 * XSTR + co];
        h8 v1 = *(const h8*)&xh[(size_t)s1 * XSTR + co];
        h8 v2 = *(const h8*)&xh[(size_t)s2 * XSTR + co];
        h8 v3 = *(const h8*)&xh[(size_t)s3 * XSTR + co];
#pragma unroll
        for (int j = 0; j < 8; ++j)
            acc[j] += ((float)v0[j] + (float)v1[j]) + ((float)v2[j] + (float)v3[j]);
    }
    for (; e < end; ++e) {
        int s = csr[e];
        h8 v = *(const h8*)&xh[(size_t)s * XSTR + co];
#pragma unroll
        for (int j = 0; j < 8; ++j) acc[j] += (float)v[j];
    }
    float dv = dinv[n];
    h8 o;
#pragma unroll
    for (int j = 0; j < 8; ++j) o[j] = (_Float16)(acc[j] * dv);
    *(h8*)&ax[(size_t)n * XSTR + co] = o;
}

// ---------------- aggregation (112 cols) + bias + relu + BN ----------------

__global__ __launch_bounds__(256) void k_agg(
    const _Float16* __restrict__ hs, const int* __restrict__ rowp,
    const int* __restrict__ csr, const float* __restrict__ dinv,
    const float* __restrict__ prm, _Float16* __restrict__ out) {
    int l = threadIdx.x;
    int q = l >> 4, sub = l & 15;
    if (sub >= 14) return;                              // cols 0..111
    int n = blockIdx.x * 16 + threadIdx.y * 4 + q;
    int co = sub * 8;
    int beg = rowp[n], end = rowp[n + 1];

    float acc[8];
    {
        h8 v = *(const h8*)&hs[(size_t)n * SP + co];
#pragma unroll
        for (int j = 0; j < 8; ++j) acc[j] = (float)v[j];
    }
    int e = beg;
    for (; e + 7 < end; e += 8) {
        int s0 = csr[e],     s1 = csr[e + 1], s2 = csr[e + 2], s3 = csr[e + 3];
        int s4 = csr[e + 4], s5 = csr[e + 5], s6 = csr[e + 6], s7 = csr[e + 7];
        h8 v0 = *(const h8*)&hs[(size_t)s0 * SP + co];
        h8 v1 = *(const h8*)&hs[(size_t)s1 * SP + co];
        h8 v2 = *(const h8*)&hs[(size_t)s2 * SP + co];
        h8 v3 = *(const h8*)&hs[(size_t)s3 * SP + co];
        h8 v4 = *(const h8*)&hs[(size_t)s4 * SP + co];
        h8 v5 = *(const h8*)&hs[(size_t)s5 * SP + co];
        h8 v6 = *(const h8*)&hs[(size_t)s6 * SP + co];
        h8 v7 = *(const h8*)&hs[(size_t)s7 * SP + co];
#pragma unroll
        for (int j = 0; j < 8; ++j)
            acc[j] += (((float)v0[j] + (float)v1[j]) + ((float)v2[j] + (float)v3[j]))
                    + (((float)v4[j] + (float)v5[j]) + ((float)v6[j] + (float)v7[j]));
    }
    for (; e + 3 < end; e += 4) {
        int s0 = csr[e], s1 = csr[e + 1], s2 = csr[e + 2], s3 = csr[e + 3];
        h8 v0 = *(const h8*)&hs[(size_t)s0 * SP + co];
        h8 v1 = *(const h8*)&hs[(size_t)s1 * SP + co];
        h8 v2 = *(const h8*)&hs[(size_t)s2 * SP + co];
        h8 v3 = *(const h8*)&hs[(size_t)s3 * SP + co];
#pragma unroll
        for (int j = 0; j < 8; ++j)
            acc[j] += ((float)v0[j] + (float)v1[j]) + ((float)v2[j] + (float)v3[j]);
    }
    for (; e < end; ++e) {
        int s = csr[e];
        h8 v = *(const h8*)&hs[(size_t)s * SP + co];
#pragma unroll
        for (int j = 0; j < 8; ++j) acc[j] += (float)v[j];
    }

    float dv = dinv[n];
    f4 bl0 = *(const f4*)&prm[co],       bl1 = *(const f4*)&prm[co + 4];
    f4 sl0 = *(const f4*)&prm[128 + co], sl1 = *(const f4*)&prm[128 + co + 4];
    f4 tl0 = *(const f4*)&prm[256 + co], tl1 = *(const f4*)&prm[256 + co + 4];
    h8 o;
    o[0] = (_Float16)(fmaxf(acc[0] * dv + bl0[0], 0.f) * sl0[0] + tl0[0]);
    o[1] = (_Float16)(fmaxf(acc[1] * dv + bl0[1], 0.f) * sl0[1] + tl0[1]);
    o[2] = (_Float16)(fmaxf(acc[2] * dv + bl0[2], 0.f) * sl0[2] + tl0[2]);
    o[3] = (_Float16)(fmaxf(acc[3] * dv + bl0[3], 0.f) * sl0[3] + tl0[3]);
    o[4] = (_Float16)(fmaxf(acc[4] * dv + bl1[0], 0.f) * sl1[0] + tl1[0]);
    o[5] = (_Float16)(fmaxf(acc[5] * dv + bl1[1], 0.f) * sl1[1] + tl1[1]);
    o[6] = (_Float16)(fmaxf(acc[6] * dv + bl1[2], 0.f) * sl1[2] + tl1[2]);
    o[7] = (_Float16)(fmaxf(acc[7] * dv + bl1[3], 0.f) * sl1[3] + tl1[3]);
    *(h8*)&out[(size_t)n * SP + co] = o;
}

// ---------------- fused dense head: 64-row blocks for occupancy ----------------
// LDS 64*136*2 = 17.4 KB; acc[4][2] -> low VGPR; grid 2x.

__global__ __launch_bounds__(256) void k_head(
    const _Float16* __restrict__ A, const h8* __restrict__ Bsw3,
    const h8* __restrict__ Bsw4, const float* __restrict__ bfold1,
    const float* __restrict__ bfold2, const float* __restrict__ fW3,
    const float* __restrict__ fb3, float* __restrict__ out) {
    __shared__ _Float16 sh[64 * LSTR];
    const int tid = threadIdx.x;
    const int w = tid >> 6, l = tid & 63;
    const int m16 = l & 15, q = l >> 4;
    const int rowbase = blockIdx.x * 64;
    const int col0 = w * 16 + m16, col1 = col0 + 64;

    h8 Bf[2][4];
    f4 acc[4][2];

    // stage A (stride SP), zero chunks 14,15
    for (int i = tid; i < 64 * 14; i += 256) {
        int r = i / 14, c = i - r * 14;
        *(h8*)&sh[r * LSTR + c * 8] = *(const h8*)&A[(size_t)(rowbase + r) * SP + c * 8];
    }
    {
        h8 z;
#pragma unroll
        for (int j = 0; j < 8; ++j) z[j] = (_Float16)0.f;
        for (int i = tid; i < 64 * 2; i += 256) {
            int r = i >> 1, c = 14 + (i & 1);
            *(h8*)&sh[r * LSTR + c * 8] = z;
        }
    }
    __syncthreads();

    // ---- GEMM fW1' (BN folded) ----
#pragma unroll
    for (int ti = 0; ti < 2; ++ti)
#pragma unroll
        for (int kc = 0; kc < 4; ++kc)
            Bf[ti][kc] = Bsw3[((w + ti * 4) * 4 + kc) * 64 + l];
#pragma unroll
    for (int mt = 0; mt < 4; ++mt) {
        acc[mt][0] = (f4){0.f, 0.f, 0.f, 0.f};
        acc[mt][1] = (f4){0.f, 0.f, 0.f, 0.f};
    }
#pragma unroll
    for (int kc = 0; kc < 4; ++kc) {
#pragma unroll
        for (int mt = 0; mt < 4; ++mt) {
            h8 a = *(const h8*)&sh[(mt * 16 + m16) * LSTR + kc * 32 + q * 8];
            acc[mt][0] = __builtin_amdgcn_mfma_f32_16x16x32_f16(a, Bf[0][kc], acc[mt][0], 0, 0, 0);
            if (w != 3)
                acc[mt][1] = __builtin_amdgcn_mfma_f32_16x16x32_f16(a, Bf[1][kc], acc[mt][1], 0, 0, 0);
        }
    }
    __syncthreads();
    {
        float bf0 = bfold1[col0], bf1 = bfold1[col1];
#pragma unroll
        for (int mt = 0; mt < 4; ++mt)
#pragma unroll
            for (int r = 0; r < 4; ++r) {
                int rl = mt * 16 + q * 4 + r;
                sh[rl * LSTR + col0] = (_Float16)fmaxf(acc[mt][0][r] + bf0, 0.f);
                sh[rl * LSTR + col1] = (_Float16)fmaxf(acc[mt][1][r] + bf1, 0.f);
            }
    }
    __syncthreads();

    // ---- GEMM fW2' (BN folded) ----
#pragma unroll
    for (int ti = 0; ti < 2; ++ti)
#pragma unroll
        for (int kc = 0; kc < 4; ++kc)
            Bf[ti][kc] = Bsw4[((w + ti * 4) * 4 + kc) * 64 + l];
#pragma unroll
    for (int mt = 0; mt < 4; ++mt) {
        acc[mt][0] = (f4){0.f, 0.f, 0.f, 0.f};
        acc[mt][1] = (f4){0.f, 0.f, 0.f, 0.f};
    }
#pragma unroll
    for (int kc = 0; kc < 4; ++kc) {
#pragma unroll
        for (int mt = 0; mt < 4; ++mt) {
            h8 a = *(const h8*)&sh[(mt * 16 + m16) * LSTR + kc * 32 + q * 8];
            acc[mt][0] = __builtin_amdgcn_mfma_f32_16x16x32_f16(a, Bf[0][kc], acc[mt][0], 0, 0, 0);
            if (w != 3)
                acc[mt][1] = __builtin_amdgcn_mfma_f32_16x16x32_f16(a, Bf[1][kc], acc[mt][1], 0, 0, 0);
        }
    }
    __syncthreads();
    {
        float bf0 = bfold2[col0], bf1 = bfold2[col1];
#pragma unroll
        for (int mt = 0; mt < 4; ++mt)
#pragma unroll
            for (int r = 0; r < 4; ++r) {
                int rl = mt * 16 + q * 4 + r;
                sh[rl * LSTR + col0] = (_Float16)fmaxf(acc[mt][0][r] + bf0, 0.f);
                sh[rl * LSTR + col1] = (_Float16)fmaxf(acc[mt][1][r] + bf1, 0.f);
            }
    }
    __syncthreads();

    // ---- 100 -> 3: quarter-wave per row (conflict-free) + 16-lane shfl reduce ----
    {
        const int qw = tid >> 4, sub = tid & 15;
#pragma unroll
        for (int pass = 0; pass < 4; ++pass) {
            int r = pass * 16 + qw;
            float p0 = 0.f, p1 = 0.f, p2 = 0.f;
            if (sub < 13) {
                h8 v = *(const h8*)&sh[r * LSTR + sub * 8];
#pragma unroll
                for (int jj = 0; jj < 8; ++jj) {
                    int c = sub * 8 + jj;
                    if (c < HID) {
                        float a = (float)v[jj];
                        p0 = fmaf(a, fW3[c * 3 + 0], p0);
                        p1 = fmaf(a, fW3[c * 3 + 1], p1);
                        p2 = fmaf(a, fW3[c * 3 + 2], p2);
                    }
                }
            }
#pragma unroll
            for (int mask = 1; mask < 16; mask <<= 1) {
                p0 += __shfl_xor(p0, mask);
                p1 += __shfl_xor(p1, mask);
                p2 += __shfl_xor(p2, mask);
            }
            if (sub == 0) {
                int grow = rowbase + r;
                if (grow < N_NODES) {
                    out[grow * 3 + 0] = fmaxf(p0 + fb3[0], 0.f);
                    out[grow * 3 + 1] = fmaxf(p1 + fb3[1], 0.f);
                    out[grow * 3 + 2] = fmaxf(p2 + fb3[2], 0.f);
                }
            }
        }
    }
}

// ---------------- launcher ----------------

extern "C" void kernel_launch(void* const* d_in, const int* in_sizes, int n_in,
                              void* d_out, int out_size, void* d_ws, size_t ws_size,
                              hipStream_t stream) {
    const float* x  = (const float*)d_in[0];
    const int*   ei = (const int*)d_in[1];
    const float* W1 = (const float*)d_in[2];  const float* b1 = (const float*)d_in[3];
    const float* g1 = (const float*)d_in[4];  const float* be1 = (const float*)d_in[5];
    const float* m1 = (const float*)d_in[6];  const float* v1 = (const float*)d_in[7];
    const float* W2 = (const float*)d_in[8];  const float* b2 = (const float*)d_in[9];
    const float* g2 = (const float*)d_in[10]; const float* be2 = (const float*)d_in[11];
    const float* m2 = (const float*)d_in[12]; const float* v2 = (const float*)d_in[13];
    const float* W3 = (const float*)d_in[14]; const float* b3 = (const float*)d_in[15];
    const float* g3 = (const float*)d_in[16]; const float* be3 = (const float*)d_in[17];
    const float* m3 = (const float*)d_in[18]; const float* v3 = (const float*)d_in[19];
    const float* fW1 = (const float*)d_in[20]; const float* fb1 = (const float*)d_in[21];
    const float* fg1 = (const float*)d_in[22]; const float* fbe1 = (const float*)d_in[23];
    const float* fm1 = (const float*)d_in[24]; const float* fv1 = (const float*)d_in[25];
    const float* fW2 = (const float*)d_in[26]; const float* fb2 = (const float*)d_in[27];
    const float* fg2 = (const float*)d_in[28]; const float* fbe2 = (const float*)d_in[29];
    const float* fm2 = (const float*)d_in[30]; const float* fv2 = (const float*)d_in[31];
    const float* fW3 = (const float*)d_in[32]; const float* fb3 = (const float*)d_in[33];
    float* out = (float*)d_out;

    char* w = (char*)d_ws;
    const size_t BUFS = (size_t)NROWS * SP * 2;         // 22,421,504 B
    _Float16* bufA = (_Float16*)(w);                    // also holds ax (stride 80)
    _Float16* bufB = (_Float16*)(w + BUFS);
    _Float16* xh   = (_Float16*)(w + 2 * BUFS);         // 16,015,360
    h8*    wsw   = (h8*)   (w + 60858368);              // 163,840
    float* bfold = (float*)(w + 61022208);              // 1,024
    float* aggp  = (float*)(w + 61023744);              // 4,608
    int*   bcur  = (int*)  (w + 61028352);              // 512
    int*   rowp  = (int*)  (w + 61028864);              // 400,128
    float* dinv  = (float*)(w + 61428992);              // 400,000
    int*   csr   = (int*)  (w + 61828992);              // 3,200,000
    int2*  bkt   = (int2*) (w + 65028992);              // 8,388,608 (end ~73.4 MB)

    (void)hipMemsetAsync(bcur, 0, NBKT * sizeof(int), stream);
    k_bin<<<(N_EDGES + 2047) / 2048, 256, 0, stream>>>(ei, bcur, bkt);
    k_local<<<NBKT, 256, 0, stream>>>(bcur, bkt, rowp, dinv, csr);
    k_cvt<<<NROWS * 10 / 256, 256, 0, stream>>>(x, dinv, xh);
    k_swz<<<48, 128, 0, stream>>>(W1, W2, W3, fW1, fW2,
                                  b1, g1, be1, m1, v1,
                                  b2, g2, be2, m2, v2,
                                  b3, g3, be3, m3, v3,
                                  fb1, fg1, fbe1, fm1, fv1,
                                  fb2, fg2, fbe2, fm2, fv2, wsw, bfold, aggp);

    const int ggrid = NROWS / 128;                      // 782
    dim3 ablk(64, 4);
    const int agrid = N_NODES / 16;                     // 6250

    // layer 1 reordered: ax = agg_norm(x), then h1 = BN1(relu(ax@W1 + b1))  (MODE 2)
    k_aggx<<<agrid, ablk, 0, stream>>>(xh, rowp, csr, dinv, bufA);
    k_gemm<3, XSTR, 2, SP><<<ggrid, 256, 0, stream>>>(bufA, wsw + 0 * 2048, nullptr, aggp + 0 * 384, bufB);
    // layer 2
    k_gemm<4, SP, 0, SP><<<ggrid, 256, 0, stream>>>(bufB, wsw + 1 * 2048, dinv, nullptr, bufA);
    k_agg<<<agrid, ablk, 0, stream>>>(bufA, rowp, csr, dinv, aggp + 1 * 384, bufB);
    // layer 3
    k_gemm<4, SP, 0, SP><<<ggrid, 256, 0, stream>>>(bufB, wsw + 2 * 2048, dinv, nullptr, bufA);
    k_agg<<<agrid, ablk, 0, stream>>>(bufA, rowp, csr, dinv, aggp + 2 * 384, bufB);
    // dense head (64-row blocks)
    k_head<<<NROWS / 64, 256, 0, stream>>>(bufB, wsw + 3 * 2048, wsw + 4 * 2048,
                                           bfold, bfold + 128, fW3, fb3, out);
}

// Round 14
// 384.825 us; speedup vs baseline: 1.2158x; 1.0221x over previous
//
#include <hip/hip_runtime.h>

#define N_NODES 100000
#define N_EDGES 800000
#define F_IN    75
#define HID     100
#define SP      112            // padded fp16 row stride (halves) for intermediates
#define XSTR    80             // fp16 row stride for converted input
#define NROWS   100096         // rows padded to multiple of 128
#define BN_EPS  1e-5f
#define LSTR    136            // LDS row stride (halves)
#define NBKT    256            // dst-range buckets
#define NPB     391            // nodes per bucket (256*391 >= 100000)
#define BIN_CAP 4096           // per-bucket global capacity (avg 3125)
#define SBCAP   24             // per-bucket LDS staging capacity in k_bin

typedef _Float16 h8 __attribute__((ext_vector_type(8)));
typedef float    f4 __attribute__((ext_vector_type(4)));

// ------------- binning: edges -> 256 dst-range buckets (coalesced appends) -----------

__global__ __launch_bounds__(256) void k_bin(const int* __restrict__ ei,
                                             int* __restrict__ bcur,
                                             int2* __restrict__ bkt) {
    __shared__ int2 sb[NBKT * SBCAP];               // 48 KB
    __shared__ int scur[NBKT], sbase[NBKT], spre[NBKT];
    int tid = threadIdx.x;
    scur[tid] = 0;
    __syncthreads();
    int base = blockIdx.x * 2048;
#pragma unroll
    for (int j = 0; j < 8; ++j) {
        int e = base + j * 256 + tid;
        if (e < N_EDGES) {
            int s = __builtin_nontemporal_load(&ei[e]);
            int d = __builtin_nontemporal_load(&ei[N_EDGES + e]);
            int b = d / NPB;
            int p = atomicAdd(&scur[b], 1);
            if (p < SBCAP) sb[b * SBCAP + p] = make_int2(s, d);
            else {                                  // rare overflow: direct append
                int gp = atomicAdd(&bcur[b], 1);
                bkt[(size_t)b * BIN_CAP + gp] = make_int2(s, d);
            }
        }
    }
    __syncthreads();
    {
        int c = scur[tid]; if (c > SBCAP) c = SBCAP;
        scur[tid] = c;
        sbase[tid] = atomicAdd(&bcur[tid], c);
        int lane = tid & 63;
        int x = c;
#pragma unroll
        for (int off = 1; off < 64; off <<= 1) {
            int y = __shfl_up(x, off);
            if (lane >= off) x += y;
        }
        spre[tid] = x;                              // per-wave inclusive
    }
    __syncthreads();
    {
        int add = 0;
        int wv = tid >> 6;
        for (int w2 = 0; w2 < wv; ++w2) add += spre[w2 * 64 + 63];
        __syncthreads();
        spre[tid] += add;
    }
    __syncthreads();
    int total = spre[NBKT - 1];
    for (int t = tid; t < total; t += 256) {
        int lo = 0, hi = NBKT - 1;
        while (lo < hi) { int mid = (lo + hi) >> 1; if (spre[mid] > t) hi = mid; else lo = mid + 1; }
        int bb = lo;
        int local = t - (spre[bb] - scur[bb]);
        bkt[(size_t)bb * BIN_CAP + sbase[bb] + local] = sb[bb * SBCAP + local];
    }
}

// ------------- per-bucket: LDS count + scan + rowp/dinv + csr scatter ---------------

__global__ __launch_bounds__(256) void k_local(const int* __restrict__ bcur,
                                               const int2* __restrict__ bkt,
                                               int* __restrict__ rowp,
                                               float* __restrict__ dinv,
                                               int* __restrict__ csr) {
    __shared__ int lcnt[512];                       // NPB=391, padded
    __shared__ int lofs[512];
    __shared__ int sbc[NBKT];
    __shared__ int swt[4];
    __shared__ int gbase_s;
    int b = blockIdx.x, tid = threadIdx.x;
    lcnt[tid] = 0; lcnt[256 + tid] = 0;
    sbc[tid] = bcur[tid];
    __syncthreads();
    if (tid == 0) { int s = 0; for (int j = 0; j < b; ++j) s += sbc[j]; gbase_s = s; }
    int cnt = sbc[b];
    const int2* bp = bkt + (size_t)b * BIN_CAP;
    int base_node = b * NPB;
    for (int i = tid; i < cnt; i += 256)
        atomicAdd(&lcnt[bp[i].y - base_node], 1);
    __syncthreads();
    int i0 = tid * 2;
    int c0 = lcnt[i0], c1 = lcnt[i0 + 1];
    int s = c0 + c1;
    int lane = tid & 63, wid = tid >> 6;
    int x = s;
#pragma unroll
    for (int off = 1; off < 64; off <<= 1) {
        int y = __shfl_up(x, off);
        if (lane >= off) x += y;
    }
    if (lane == 63) swt[wid] = x;
    __syncthreads();
    int woff = 0;
    for (int wv = 0; wv < wid; ++wv) woff += swt[wv];
    int excl = woff + x - s;
    lofs[i0] = excl;
    lofs[i0 + 1] = excl + c0;
    __syncthreads();
    int gbase = gbase_s;
    for (int i = tid; i < NPB; i += 256) {
        int node = base_node + i;
        if (node < N_NODES) {
            rowp[node] = gbase + lofs[i];
            dinv[node] = rsqrtf((float)(lcnt[i] + 1));
        }
    }
    if (b == NBKT - 1 && tid == 0) rowp[N_NODES] = N_EDGES;
    __syncthreads();
    for (int i = tid; i < cnt; i += 256) {
        int2 p = bp[i];
        int pos = atomicAdd(&lofs[p.y - base_node], 1);
        csr[gbase + pos] = p.x;
    }
}

// -------- x -> fp16 * dinv[row] (stride 80, zero pad cols 75..79, rows >= N) --------

__global__ __launch_bounds__(256) void k_cvt(const float* __restrict__ x,
                                             const float* __restrict__ dinv,
                                             _Float16* __restrict__ xh) {
    int id = blockIdx.x * 256 + threadIdx.x;        // NROWS*10 chunks
    int r = id / 10, c0 = (id - r * 10) * 8;
    h8 o;
#pragma unroll
    for (int j = 0; j < 8; ++j) o[j] = (_Float16)0.f;
    if (r < N_NODES) {
        float dv = dinv[r];
        const float* xr = x + (size_t)r * F_IN;
#pragma unroll
        for (int j = 0; j < 8; ++j) {
            int c = c0 + j;
            if (c < F_IN) o[j] = (_Float16)(__builtin_nontemporal_load(&xr[c]) * dv);
        }
    }
    *(h8*)&xh[(size_t)r * XSTR + c0] = o;
}

// ---------------- weight swizzle + param folding ----------------

__global__ __launch_bounds__(128) void k_swz(
    const float* __restrict__ W1, const float* __restrict__ W2,
    const float* __restrict__ W3, const float* __restrict__ fW1,
    const float* __restrict__ fW2,
    const float* __restrict__ b1, const float* __restrict__ g1,
    const float* __restrict__ be1, const float* __restrict__ m1,
    const float* __restrict__ v1,
    const float* __restrict__ b2, const float* __restrict__ g2,
    const float* __restrict__ be2, const float* __restrict__ m2,
    const float* __restrict__ v2,
    const float* __restrict__ b3, const float* __restrict__ g3,
    const float* __restrict__ be3, const float* __restrict__ m3,
    const float* __restrict__ v3,
    const float* __restrict__ fb1, const float* __restrict__ fg1,
    const float* __restrict__ fbe1, const float* __restrict__ fm1,
    const float* __restrict__ fv1,
    const float* __restrict__ fb2, const float* __restrict__ fg2,
    const float* __restrict__ fbe2, const float* __restrict__ fm2,
    const float* __restrict__ fv2,
    h8* __restrict__ wsw, float* __restrict__ bfold, float* __restrict__ aggp) {
    int mat = blockIdx.x >> 3, tile = blockIdx.x & 7;
    int tid = threadIdx.x;

    if (mat == 5) {                       // agg params: tile 0,1,2 -> GCN layers 1,2,3
        if (tile > 2) return;
        const float *bb, *gg, *be, *mm, *vv;
        if (tile == 0) { bb = b1; gg = g1; be = be1; mm = m1; vv = v1; }
        else if (tile == 1) { bb = b2; gg = g2; be = be2; mm = m2; vv = v2; }
        else { bb = b3; gg = g3; be = be3; mm = m3; vv = v3; }
        int c = tid;
        float b = 0.f, s = 0.f, t = 0.f;
        if (c < HID) {
            b = bb[c];
            s = gg[c] * rsqrtf(vv[c] + BN_EPS);
            t = be[c] - mm[c] * s;
        }
        aggp[tile * 384 + c] = b;
        aggp[tile * 384 + 128 + c] = s;
        aggp[tile * 384 + 256 + c] = t;
        return;
    }

    const float* W; int K;
    const float *bb = nullptr, *gg = nullptr, *be = nullptr, *mm = nullptr, *vv = nullptr;
    bool fold = false;
    switch (mat) {
        case 0: W = W1; K = F_IN; break;
        case 1: W = W2; K = HID; break;
        case 2: W = W3; K = HID; break;
        case 3: W = fW1; K = HID; fold = true; bb = fb1; gg = fg1; be = fbe1; mm = fm1; vv = fv1; break;
        default: W = fW2; K = HID; fold = true; bb = fb2; gg = fg2; be = fbe2; mm = fm2; vv = fv2; break;
    }
    if (tid < 64) {
        int m16 = tid & 15, q = tid >> 4;
        int n = tile * 16 + m16;
        float sn = 1.f;
        if (fold && n < HID) sn = gg[n] * rsqrtf(vv[n] + BN_EPS);
        for (int kc = 0; kc < 4; ++kc) {
            h8 b;
#pragma unroll
            for (int j = 0; j < 8; ++j) {
                int k = kc * 32 + q * 8 + j;
                float v = (k < K && n < HID) ? W[k * HID + n] * sn : 0.f;
                b[j] = (_Float16)v;
            }
            wsw[((size_t)mat * 8 + tile) * 256 + kc * 64 + tid] = b;
        }
    }
    if (fold && tile == 0) {
        int c = tid;
        float v = 0.f;
        if (c < HID) {
            float s = gg[c] * rsqrtf(vv[c] + BN_EPS);
            float t = be[c] - mm[c] * s;
            v = bb[c] * s + t;
        }
        bfold[(mat - 3) * 128 + c] = v;
    }
}

// ---------------- MFMA GEMM (64-row blocks for occupancy) ----------------
// MODE 0: out = acc * dinv[row]
// MODE 2: out = relu(acc + prm[col]) * prm[128+col] + prm[256+col]   (GCN layer 1)

template <int KC, int ASTR, int MODE, int OSTR>
__global__ __launch_bounds__(256) void k_gemm(
    const _Float16* __restrict__ A, const h8* __restrict__ Bsw,
    const float* __restrict__ dinv, const float* __restrict__ prm,
    _Float16* __restrict__ out) {
    __shared__ _Float16 As[64 * LSTR];              // 17.4 KB
    const int tid = threadIdx.x;
    const int w = tid >> 6, l = tid & 63;
    const int m16 = l & 15, q = l >> 4;
    const int rowbase = blockIdx.x * 64;

    h8 Bf[2][KC];
#pragma unroll
    for (int ti = 0; ti < 2; ++ti)
#pragma unroll
        for (int kc = 0; kc < KC; ++kc)
            Bf[ti][kc] = Bsw[((w + ti * 4) * 4 + kc) * 64 + l];

    constexpr int NCH = ASTR / 8;
    for (int i = tid; i < 64 * NCH; i += 256) {
        int r = i / NCH, c = i - r * NCH;
        *(h8*)&As[r * LSTR + c * 8] = *(const h8*)&A[(size_t)(rowbase + r) * ASTR + c * 8];
    }
    {
        constexpr int ZCH = (KC * 32 - ASTR) / 8;   // 2 in both configs
        h8 z;
#pragma unroll
        for (int j = 0; j < 8; ++j) z[j] = (_Float16)0.f;
        for (int i = tid; i < 64 * ZCH; i += 256) {
            int r = i / ZCH, c = NCH + (i - r * ZCH);
            *(h8*)&As[r * LSTR + c * 8] = z;
        }
    }
    __syncthreads();

    f4 acc[4][2];
#pragma unroll
    for (int mt = 0; mt < 4; ++mt) {
        acc[mt][0] = (f4){0.f, 0.f, 0.f, 0.f};
        acc[mt][1] = (f4){0.f, 0.f, 0.f, 0.f};
    }
#pragma unroll
    for (int kc = 0; kc < KC; ++kc) {
#pragma unroll
        for (int mt = 0; mt < 4; ++mt) {
            h8 a = *(const h8*)&As[(mt * 16 + m16) * LSTR + kc * 32 + q * 8];
            acc[mt][0] = __builtin_amdgcn_mfma_f32_16x16x32_f16(a, Bf[0][kc], acc[mt][0], 0, 0, 0);
            if (w != 3)
                acc[mt][1] = __builtin_amdgcn_mfma_f32_16x16x32_f16(a, Bf[1][kc], acc[mt][1], 0, 0, 0);
        }
    }
    __syncthreads();                                // all MFMA LDS reads done

    const int col0 = w * 16 + m16;
    const int col1 = col0 + 64;
    if (MODE == 2) {
        float b0 = prm[col0],       b1 = prm[col1];
        float s0 = prm[128 + col0], s1 = prm[128 + col1];
        float t0 = prm[256 + col0], t1 = prm[256 + col1];
#pragma unroll
        for (int mt = 0; mt < 4; ++mt)
#pragma unroll
            for (int r = 0; r < 4; ++r) {
                int rl = mt * 16 + q * 4 + r;
                As[rl * LSTR + col0] = (_Float16)(fmaxf(acc[mt][0][r] + b0, 0.f) * s0 + t0);
                As[rl * LSTR + col1] = (_Float16)(fmaxf(acc[mt][1][r] + b1, 0.f) * s1 + t1);
            }
    } else {
#pragma unroll
        for (int mt = 0; mt < 4; ++mt)
#pragma unroll
            for (int r = 0; r < 4; ++r) {
                int rl = mt * 16 + q * 4 + r;
                int row = rowbase + rl;
                int dr = row < N_NODES ? row : N_NODES - 1;
                float dv = dinv[dr];
                As[rl * LSTR + col0] = (_Float16)(acc[mt][0][r] * dv);
                As[rl * LSTR + col1] = (_Float16)(acc[mt][1][r] * dv);
            }
    }
    __syncthreads();

    constexpr int OCH = OSTR / 8;                   // 14
    for (int i = tid; i < 64 * OCH; i += 256) {
        int r = i / OCH, c = i - r * OCH;
        *(h8*)&out[(size_t)(rowbase + r) * OSTR + c * 8] = *(const h8*)&As[r * LSTR + c * 8];
    }
}

// ------------- layer-1 aggregate on x (80 cols): ax = agg(xh)*dinv[n] ---------------

__global__ __launch_bounds__(256) void k_aggx(
    const _Float16* __restrict__ xh, const int* __restrict__ rowp,
    const int* __restrict__ csr, const float* __restrict__ dinv,
    _Float16* __restrict__ ax) {
    int l = threadIdx.x;
    int q = l >> 4, sub = l & 15;
    if (sub >= 10) return;                          // 80 cols
    int n = blockIdx.x * 16 + threadIdx.y * 4 + q;
    int co = sub * 8;
    int beg = rowp[n], end = rowp[n + 1];

    float acc[8];
    {
        h8 v = *(const h8*)&xh[(size_t)n * XSTR + co];
#pragma unroll
        for (int j = 0; j < 8; ++j) acc[j] = (float)v[j];
    }
    int e = beg;
    for (; e + 7 < end; e += 8) {
        int s0 = csr[e],     s1 = csr[e + 1], s2 = csr[e + 2], s3 = csr[e + 3];
        int s4 = csr[e + 4], s5 = csr[e + 5], s6 = csr[e + 6], s7 = csr[e + 7];
        h8 v0 = *(const h8*)&xh[(size_t)s0 * XSTR + co];
        h8 v1 = *(const h8*)&xh[(size_t)s1 * XSTR + co];
        h8 v2 = *(const h8*)&xh[(size_t)s2 * XSTR + co];
        h8 v3 = *(const h8*)&xh[(size_t)s3 * XSTR + co];
        h8 v4 = *(const h8*)&xh[(size_t)s4 * XSTR + co];
        h8 v5 = *(const h8*)&xh[(size_t)s5 * XSTR + co];
        h8 v6 = *(const h8*)&xh[(size_t)s6 * XSTR + co];
        h8 v7 = *(const h8*)&xh[(size_t)s7 * XSTR + co];
#pragma unroll
        for (int j = 0; j < 8; ++j)
            acc[j] += (((float)v0[j] + (float)v1[j]) + ((float)v2[j] + (float)v3[j]))
                    + (((float)v4[j] + (float)v5[j]) + ((float)v6[j] + (float)v7[j]));
    }
    for (; e + 3 < end; e += 4) {
        int s0 = csr[e], s1 = csr[e + 1], s2 = csr[e + 2], s3 = csr[e + 3];
        h8 v0 = *(const h8*)&xh[(size_t)s0 * XSTR + co];
        h8 v1 = *(const h8*)&xh[(size_t)s1 * XSTR + co];
        h8 v2 = *(const h8*)&xh[(size_t)s2 * XSTR + co];
        h8 v3 = *(const h8*)&xh[(size_t)s3 * XSTR + co];
#pragma unroll
        for (int j = 0; j < 8; ++j)
            acc[j] += ((float)v0[j] + (float)v1[j]) + ((float)v2[j] + (float)v3[j]);
    }
    for (; e < end; ++e) {
        int s = csr[e];
        h8 v = *(const h8*)&xh[(size_t)s * XSTR + co];
#pragma unroll
        for (int j = 0; j < 8; ++j) acc[j] += (float)v[j];
    }
    float dv = dinv[n];
    h8 o;
#pragma unroll
    for (int j = 0; j < 8; ++j) o[j] = (_Float16)(acc[j] * dv);
    *(h8*)&ax[(size_t)n * XSTR + co] = o;
}

// ---------------- aggregation (112 cols) + bias + relu + BN ----------------

__global__ __launch_bounds__(256) void k_agg(
    const _Float16* __restrict__ hs, const int* __restrict__ rowp,
    const int* __restrict__ csr, const float* __restrict__ dinv,
    const float* __restrict__ prm, _Float16* __restrict__ out) {
    int l = threadIdx.x;
    int q = l >> 4, sub = l & 15;
    if (sub >= 14) return;                          // cols 0..111
    int n = blockIdx.x * 16 + threadIdx.y * 4 + q;
    int co = sub * 8;
    int beg = rowp[n], end = rowp[n + 1];

    float acc[8];
    {
        h8 v = *(const h8*)&hs[(size_t)n * SP + co];
#pragma unroll
        for (int j = 0; j < 8; ++j) acc[j] = (float)v[j];
    }
    int e = beg;
    for (; e + 7 < end; e += 8) {
        int s0 = csr[e],     s1 = csr[e + 1], s2 = csr[e + 2], s3 = csr[e + 3];
        int s4 = csr[e + 4], s5 = csr[e + 5], s6 = csr[e + 6], s7 = csr[e + 7];
        h8 v0 = *(const h8*)&hs[(size_t)s0 * SP + co];
        h8 v1 = *(const h8*)&hs[(size_t)s1 * SP + co];
        h8 v2 = *(const h8*)&hs[(size_t)s2 * SP + co];
        h8 v3 = *(const h8*)&hs[(size_t)s3 * SP + co];
        h8 v4 = *(const h8*)&hs[(size_t)s4 * SP + co];
        h8 v5 = *(const h8*)&hs[(size_t)s5 * SP + co];
        h8 v6 = *(const h8*)&hs[(size_t)s6 * SP + co];
        h8 v7 = *(const h8*)&hs[(size_t)s7 * SP + co];
#pragma unroll
        for (int j = 0; j < 8; ++j)
            acc[j] += (((float)v0[j] + (float)v1[j]) + ((float)v2[j] + (float)v3[j]))
                    + (((float)v4[j] + (float)v5[j]) + ((float)v6[j] + (float)v7[j]));
    }
    for (; e + 3 < end; e += 4) {
        int s0 = csr[e], s1 = csr[e + 1], s2 = csr[e + 2], s3 = csr[e + 3];
        h8 v0 = *(const h8*)&hs[(size_t)s0 * SP + co];
        h8 v1 = *(const h8*)&hs[(size_t)s1 * SP + co];
        h8 v2 = *(const h8*)&hs[(size_t)s2 * SP + co];
        h8 v3 = *(const h8*)&hs[(size_t)s3 * SP + co];
#pragma unroll
        for (int j = 0; j < 8; ++j)
            acc[j] += ((float)v0[j] + (float)v1[j]) + ((float)v2[j] + (float)v3[j]);
    }
    for (; e < end; ++e) {
        int s = csr[e];
        h8 v = *(const h8*)&hs[(size_t)s * SP + co];
#pragma unroll
        for (int j = 0; j < 8; ++j) acc[j] += (float)v[j];
    }

    float dv = dinv[n];
    f4 bl0 = *(const f4*)&prm[co],       bl1 = *(const f4*)&prm[co + 4];
    f4 sl0 = *(const f4*)&prm[128 + co], sl1 = *(const f4*)&prm[128 + co + 4];
    f4 tl0 = *(const f4*)&prm[256 + co], tl1 = *(const f4*)&prm[256 + co + 4];
    h8 o;
    o[0] = (_Float16)(fmaxf(acc[0] * dv + bl0[0], 0.f) * sl0[0] + tl0[0]);
    o[1] = (_Float16)(fmaxf(acc[1] * dv + bl0[1], 0.f) * sl0[1] + tl0[1]);
    o[2] = (_Float16)(fmaxf(acc[2] * dv + bl0[2], 0.f) * sl0[2] + tl0[2]);
    o[3] = (_Float16)(fmaxf(acc[3] * dv + bl0[3], 0.f) * sl0[3] + tl0[3]);
    o[4] = (_Float16)(fmaxf(acc[4] * dv + bl1[0], 0.f) * sl1[0] + tl1[0]);
    o[5] = (_Float16)(fmaxf(acc[5] * dv + bl1[1], 0.f) * sl1[1] + tl1[1]);
    o[6] = (_Float16)(fmaxf(acc[6] * dv + bl1[2], 0.f) * sl1[2] + tl1[2]);
    o[7] = (_Float16)(fmaxf(acc[7] * dv + bl1[3], 0.f) * sl1[3] + tl1[3]);
    *(h8*)&out[(size_t)n * SP + co] = o;
}

// ---------------- fused dense head: 64-row blocks ----------------

__global__ __launch_bounds__(256) void k_head(
    const _Float16* __restrict__ A, const h8* __restrict__ Bsw3,
    const h8* __restrict__ Bsw4, const float* __restrict__ bfold1,
    const float* __restrict__ bfold2, const float* __restrict__ fW3,
    const float* __restrict__ fb3, float* __restrict__ out) {
    __shared__ _Float16 sh[64 * LSTR];
    const int tid = threadIdx.x;
    const int w = tid >> 6, l = tid & 63;
    const int m16 = l & 15, q = l >> 4;
    const int rowbase = blockIdx.x * 64;
    const int col0 = w * 16 + m16, col1 = col0 + 64;

    h8 Bf[2][4];
    f4 acc[4][2];

    for (int i = tid; i < 64 * 14; i += 256) {
        int r = i / 14, c = i - r * 14;
        *(h8*)&sh[r * LSTR + c * 8] = *(const h8*)&A[(size_t)(rowbase + r) * SP + c * 8];
    }
    {
        h8 z;
#pragma unroll
        for (int j = 0; j < 8; ++j) z[j] = (_Float16)0.f;
        for (int i = tid; i < 64 * 2; i += 256) {
            int r = i >> 1, c = 14 + (i & 1);
            *(h8*)&sh[r * LSTR + c * 8] = z;
        }
    }
    __syncthreads();

    // ---- GEMM fW1' (BN folded) ----
#pragma unroll
    for (int ti = 0; ti < 2; ++ti)
#pragma unroll
        for (int kc = 0; kc < 4; ++kc)
            Bf[ti][kc] = Bsw3[((w + ti * 4) * 4 + kc) * 64 + l];
#pragma unroll
    for (int mt = 0; mt < 4; ++mt) {
        acc[mt][0] = (f4){0.f, 0.f, 0.f, 0.f};
        acc[mt][1] = (f4){0.f, 0.f, 0.f, 0.f};
    }
#pragma unroll
    for (int kc = 0; kc < 4; ++kc) {
#pragma unroll
        for (int mt = 0; mt < 4; ++mt) {
            h8 a = *(const h8*)&sh[(mt * 16 + m16) * LSTR + kc * 32 + q * 8];
            acc[mt][0] = __builtin_amdgcn_mfma_f32_16x16x32_f16(a, Bf[0][kc], acc[mt][0], 0, 0, 0);
            if (w != 3)
                acc[mt][1] = __builtin_amdgcn_mfma_f32_16x16x32_f16(a, Bf[1][kc], acc[mt][1], 0, 0, 0);
        }
    }
    __syncthreads();
    {
        float bf0 = bfold1[col0], bf1 = bfold1[col1];
#pragma unroll
        for (int mt = 0; mt < 4; ++mt)
#pragma unroll
            for (int r = 0; r < 4; ++r) {
                int rl = mt * 16 + q * 4 + r;
                sh[rl * LSTR + col0] = (_Float16)fmaxf(acc[mt][0][r] + bf0, 0.f);
                sh[rl * LSTR + col1] = (_Float16)fmaxf(acc[mt][1][r] + bf1, 0.f);
            }
    }
    __syncthreads();

    // ---- GEMM fW2' (BN folded) ----
#pragma unroll
    for (int ti = 0; ti < 2; ++ti)
#pragma unroll
        for (int kc = 0; kc < 4; ++kc)
            Bf[ti][kc] = Bsw4[((w + ti * 4) * 4 + kc) * 64 + l];
#pragma unroll
    for (int mt = 0; mt < 4; ++mt) {
        acc[mt][0] = (f4){0.f, 0.f, 0.f, 0.f};
        acc[mt][1] = (f4){0.f, 0.f, 0.f, 0.f};
    }
#pragma unroll
    for (int kc = 0; kc < 4; ++kc) {
#pragma unroll
        for (int mt = 0; mt < 4; ++mt) {
            h8 a = *(const h8*)&sh[(mt * 16 + m16) * LSTR + kc * 32 + q * 8];
            acc[mt][0] = __builtin_amdgcn_mfma_f32_16x16x32_f16(a, Bf[0][kc], acc[mt][0], 0, 0, 0);
            if (w != 3)
                acc[mt][1] = __builtin_amdgcn_mfma_f32_16x16x32_f16(a, Bf[1][kc], acc[mt][1], 0, 0, 0);
        }
    }
    __syncthreads();
    {
        float bf0 = bfold2[col0], bf1 = bfold2[col1];
#pragma unroll
        for (int mt = 0; mt < 4; ++mt)
#pragma unroll
            for (int r = 0; r < 4; ++r) {
                int rl = mt * 16 + q * 4 + r;
                sh[rl * LSTR + col0] = (_Float16)fmaxf(acc[mt][0][r] + bf0, 0.f);
                sh[rl * LSTR + col1] = (_Float16)fmaxf(acc[mt][1][r] + bf1, 0.f);
            }
    }
    __syncthreads();

    // ---- 100 -> 3: quarter-wave per row (conflict-free) + 16-lane shfl reduce ----
    {
        const int qw = tid >> 4, sub = tid & 15;
#pragma unroll
        for (int pass = 0; pass < 4; ++pass) {
            int r = pass * 16 + qw;
            float p0 = 0.f, p1 = 0.f, p2 = 0.f;
            if (sub < 13) {
                h8 v = *(const h8*)&sh[r * LSTR + sub * 8];
#pragma unroll
                for (int jj = 0; jj < 8; ++jj) {
                    int c = sub * 8 + jj;
                    if (c < HID) {
                        float a = (float)v[jj];
                        p0 = fmaf(a, fW3[c * 3 + 0], p0);
                        p1 = fmaf(a, fW3[c * 3 + 1], p1);
                        p2 = fmaf(a, fW3[c * 3 + 2], p2);
                    }
                }
            }
#pragma unroll
            for (int mask = 1; mask < 16; mask <<= 1) {
                p0 += __shfl_xor(p0, mask);
                p1 += __shfl_xor(p1, mask);
                p2 += __shfl_xor(p2, mask);
            }
            if (sub == 0) {
                int grow = rowbase + r;
                if (grow < N_NODES) {
                    out[grow * 3 + 0] = fmaxf(p0 + fb3[0], 0.f);
                    out[grow * 3 + 1] = fmaxf(p1 + fb3[1], 0.f);
                    out[grow * 3 + 2] = fmaxf(p2 + fb3[2], 0.f);
                }
            }
        }
    }
}

// ---------------- launcher ----------------

extern "C" void kernel_launch(void* const* d_in, const int* in_sizes, int n_in,
                              void* d_out, int out_size, void* d_ws, size_t ws_size,
                              hipStream_t stream) {
    const float* x  = (const float*)d_in[0];
    const int*   ei = (const int*)d_in[1];
    const float* W1 = (const float*)d_in[2];  const float* b1 = (const float*)d_in[3];
    const float* g1 = (const float*)d_in[4];  const float* be1 = (const float*)d_in[5];
    const float* m1 = (const float*)d_in[6];  const float* v1 = (const float*)d_in[7];
    const float* W2 = (const float*)d_in[8];  const float* b2 = (const float*)d_in[9];
    const float* g2 = (const float*)d_in[10]; const float* be2 = (const float*)d_in[11];
    const float* m2 = (const float*)d_in[12]; const float* v2 = (const float*)d_in[13];
    const float* W3 = (const float*)d_in[14]; const float* b3 = (const float*)d_in[15];
    const float* g3 = (const float*)d_in[16]; const float* be3 = (const float*)d_in[17];
    const float* m3 = (const float*)d_in[18]; const float* v3 = (const float*)d_in[19];
    const float* fW1 = (const float*)d_in[20]; const float* fb1 = (const float*)d_in[21];
    const float* fg1 = (const float*)d_in[22]; const float* fbe1 = (const float*)d_in[23];
    const float* fm1 = (const float*)d_in[24]; const float* fv1 = (const float*)d_in[25];
    const float* fW2 = (const float*)d_in[26]; const float* fb2 = (const float*)d_in[27];
    const float* fg2 = (const float*)d_in[28]; const float* fbe2 = (const float*)d_in[29];
    const float* fm2 = (const float*)d_in[30]; const float* fv2 = (const float*)d_in[31];
    const float* fW3 = (const float*)d_in[32]; const float* fb3 = (const float*)d_in[33];
    float* out = (float*)d_out;

    char* w = (char*)d_ws;
    const size_t BUFS = (size_t)NROWS * SP * 2;         // 22,421,504 B
    _Float16* bufA = (_Float16*)(w);                    // also holds ax (stride 80)
    _Float16* bufB = (_Float16*)(w + BUFS);
    _Float16* xh   = (_Float16*)(w + 2 * BUFS);         // 16,015,360
    h8*    wsw   = (h8*)   (w + 60858368);              // 163,840
    float* bfold = (float*)(w + 61022208);              // 1,024
    float* aggp  = (float*)(w + 61023744);              // 4,608
    int*   bcur  = (int*)  (w + 61028352);              // 1,024
    int*   rowp  = (int*)  (w + 61029376);              // 400,128
    float* dinv  = (float*)(w + 61429504);              // 400,000
    int*   csr   = (int*)  (w + 61829504);              // 3,200,000
    int2*  bkt   = (int2*) (w + 65029504);              // 8,388,608 (end ~73.4 MB)

    (void)hipMemsetAsync(bcur, 0, NBKT * sizeof(int), stream);
    k_bin<<<(N_EDGES + 2047) / 2048, 256, 0, stream>>>(ei, bcur, bkt);
    k_local<<<NBKT, 256, 0, stream>>>(bcur, bkt, rowp, dinv, csr);
    k_cvt<<<NROWS * 10 / 256, 256, 0, stream>>>(x, dinv, xh);
    k_swz<<<48, 128, 0, stream>>>(W1, W2, W3, fW1, fW2,
                                  b1, g1, be1, m1, v1,
                                  b2, g2, be2, m2, v2,
                                  b3, g3, be3, m3, v3,
                                  fb1, fg1, fbe1, fm1, fv1,
                                  fb2, fg2, fbe2, fm2, fv2, wsw, bfold, aggp);

    const int ggrid = NROWS / 64;                       // 1564
    dim3 ablk(64, 4);
    const int agrid = N_NODES / 16;                     // 6250

    // layer 1 reordered: ax = agg_norm(x), then h1 = BN1(relu(ax@W1 + b1))  (MODE 2)
    k_aggx<<<agrid, ablk, 0, stream>>>(xh, rowp, csr, dinv, bufA);
    k_gemm<3, XSTR, 2, SP><<<ggrid, 256, 0, stream>>>(bufA, wsw + 0 * 2048, nullptr, aggp + 0 * 384, bufB);
    // layer 2
    k_gemm<4, SP, 0, SP><<<ggrid, 256, 0, stream>>>(bufB, wsw + 1 * 2048, dinv, nullptr, bufA);
    k_agg<<<agrid, ablk, 0, stream>>>(bufA, rowp, csr, dinv, aggp + 1 * 384, bufB);
    // layer 3
    k_gemm<4, SP, 0, SP><<<ggrid, 256, 0, stream>>>(bufB, wsw + 2 * 2048, dinv, nullptr, bufA);
    k_agg<<<agrid, ablk, 0, stream>>>(bufA, rowp, csr, dinv, aggp + 2 * 384, bufB);
    // dense head (64-row blocks)
    k_head<<<NROWS / 64, 256, 0, stream>>>(bufB, wsw + 3 * 2048, wsw + 4 * 2048,
                                           bfold, bfold + 128, fW3, fb3, out);
}